// Round 1
// baseline (2865.340 us; speedup 1.0000x reference)
//
#include <hip/hip_runtime.h>
#include <math.h>

// Problem constants
#define HH 32
#define WW 32
#define PADW 36
#define PPLANE (36*36)   // padded plane elements
#define TX 6
#define NB 2             // batch m
#define NSTA 35

__device__ __forceinline__ float sigf(float x) { return 1.0f / (1.0f + __expf(-x)); }

// ---------------------------------------------------------------------------
// Stage x_t (11 channels) into padded P1[cur] channels [0,11)
// ---------------------------------------------------------------------------
__global__ __launch_bounds__(256) void stage_x_kernel(const float* __restrict__ X,
                                                      float* __restrict__ P1cur, int t) {
    int i = blockIdx.x * 256 + threadIdx.x;       // over 2*11*1024
    if (i >= NB * 11 * 1024) return;
    int pix = i & 1023;
    int c   = (i >> 10) % 11;
    int b   = i / (11 * 1024);
    int y = pix >> 5, x = pix & 31;
    P1cur[(b * 75 + c) * PPLANE + (y + 2) * PADW + (x + 2)] =
        X[(((b * TX + t) * 11 + c) << 10) + pix];
}

// ---------------------------------------------------------------------------
// Fused ConvLSTM cell: 5x5 conv over padded concat input + LSTM gate update.
// One thread: 1 hidden channel (all 4 gates) x 2 pixels.
// grid = (2 pixel-halves, CH, 2 batch), block = 256.
// ---------------------------------------------------------------------------
template <int CTOT, int CH>
__global__ __launch_bounds__(256) void cell_kernel(
    const float* __restrict__ Pin,   // (2, CTOT, 36, 36) padded concat input
    const float* __restrict__ Wt,    // (4*CH, CTOT, 5, 5)
    const float* __restrict__ Bias,  // (4*CH)
    float* __restrict__ Cst,         // (2, CH, 32, 32) cell state, in/out
    float* __restrict__ outA, int caTot,   // padded out (pre-offset to ch base)
    float* __restrict__ outB, int cbTot,   // optional 2nd padded out
    float* __restrict__ outP)              // optional plain (2,CH,32,32) out
{
    const int half = blockIdx.x;
    const int hc   = blockIdx.y;
    const int b    = blockIdx.z;
    const int tid  = threadIdx.x;
    const int pix0 = half * 512 + tid;            // this thread: pix0, pix0+256
    const int y0 = pix0 >> 5, x0 = pix0 & 31;

    const float* ip = Pin + (b * CTOT * PADW + y0) * PADW + x0;
    const int wstride = CH * CTOT * 25;
    const float* wi = Wt + hc * (CTOT * 25);
    const float* wf = wi + wstride;
    const float* wo = wf + wstride;
    const float* wg = wo + wstride;

    float ai0 = Bias[hc],          ai1 = ai0;
    float af0 = Bias[CH + hc],     af1 = af0;
    float ao0 = Bias[2 * CH + hc], ao1 = ao0;
    float ag0 = Bias[3 * CH + hc], ag1 = ag0;

    for (int cin = 0; cin < CTOT; ++cin) {
#pragma unroll
        for (int k = 0; k < 25; ++k) {
            const int dy = k / 5, dx = k - dy * 5;
            const float v0 = ip[dy * PADW + dx];
            const float v1 = ip[8 * PADW + dy * PADW + dx];   // pixel +256 = +8 rows
            const float a = wi[k], f = wf[k], o = wo[k], g = wg[k];
            ai0 = fmaf(v0, a, ai0); ai1 = fmaf(v1, a, ai1);
            af0 = fmaf(v0, f, af0); af1 = fmaf(v1, f, af1);
            ao0 = fmaf(v0, o, ao0); ao1 = fmaf(v1, o, ao1);
            ag0 = fmaf(v0, g, ag0); ag1 = fmaf(v1, g, ag1);
        }
        ip += PPLANE; wi += 25; wf += 25; wo += 25; wg += 25;
    }

    const float aI[2] = {ai0, ai1}, aF[2] = {af0, af1};
    const float aO[2] = {ao0, ao1}, aG[2] = {ag0, ag1};
#pragma unroll
    for (int p = 0; p < 2; ++p) {
        const int pix = pix0 + p * 256;
        const int y = pix >> 5, x = pix & 31;
        const int idxC = ((b * CH + hc) << 10) + pix;
        const float c_old = Cst[idxC];
        const float cn = sigf(aF[p]) * c_old + sigf(aI[p]) * tanhf(aG[p]);
        const float hn = sigf(aO[p]) * tanhf(cn);
        Cst[idxC] = cn;
        const int ppos = (y + 2) * PADW + (x + 2);
        outA[(b * caTot + hc) * PPLANE + ppos] = hn;
        if (outB) outB[(b * cbTot + hc) * PPLANE + ppos] = hn;
        if (outP) outP[idxC] = hn;
    }
}

// ---------------------------------------------------------------------------
// meo head: 1x1 conv 128 -> 5.  grid = (4 pix-quarters, 5 oc, 2 b)
// ---------------------------------------------------------------------------
__global__ __launch_bounds__(256) void meo_kernel(const float* __restrict__ H3,
                                                  const float* __restrict__ Wm,
                                                  const float* __restrict__ bm,
                                                  float* __restrict__ out, int t) {
    const int pix = blockIdx.x * 256 + threadIdx.x;
    const int oc = blockIdx.y, b = blockIdx.z;
    float acc = bm[oc];
    const float* w = Wm + oc * 128;
    const float* h = H3 + ((b * 128) << 10) + pix;
#pragma unroll 8
    for (int c = 0; c < 128; ++c) acc = fmaf(w[c], h[c << 10], acc);
    out[2520 + (b * TX + t) * 5120 + (oc << 10) + pix] = acc;
}

// ---------------------------------------------------------------------------
// aqi head: per (station, b): gather 128x3x3 patch -> MLP 1152->256->6
// grid = (35, 2), block = 256
// ---------------------------------------------------------------------------
__global__ __launch_bounds__(256) void aqi_kernel(const float* __restrict__ H3,
                                                  const float* __restrict__ Wf1,
                                                  const float* __restrict__ bf1,
                                                  const float* __restrict__ Wf2,
                                                  const float* __restrict__ bf2,
                                                  const int* __restrict__ locs,
                                                  float* __restrict__ out, int t) {
    __shared__ float feats[1152];
    __shared__ float hid[256];
    const int s = blockIdx.x, b = blockIdx.y, tid = threadIdx.x;
    const int y0 = locs[2 * s], x0 = locs[2 * s + 1];
    for (int k = tid; k < 1152; k += 256) {
        const int c = k / 9, r = k % 9;
        const int i = r / 3, j = r % 3;
        feats[k] = H3[((b * 128 + c) << 10) + (y0 + i) * 32 + (x0 + j)];
    }
    __syncthreads();
    float acc = bf1[tid];
    for (int k = 0; k < 1152; ++k) acc = fmaf(feats[k], Wf1[k * 256 + tid], acc);
    hid[tid] = tanhf(acc);
    __syncthreads();
    if (tid < 6) {
        float a = bf2[tid];
        for (int k = 0; k < 256; ++k) a = fmaf(hid[k], Wf2[k * 6 + tid], a);
        out[(b * TX + t) * 210 + s * 6 + tid] = a;
    }
}

// ---------------------------------------------------------------------------
extern "C" void kernel_launch(void* const* d_in, const int* in_sizes, int n_in,
                              void* d_out, int out_size, void* d_ws, size_t ws_size,
                              hipStream_t stream) {
    const float* X   = (const float*)d_in[0];
    const float* W1  = (const float*)d_in[1];
    const float* b1  = (const float*)d_in[2];
    const float* W2  = (const float*)d_in[3];
    const float* b2  = (const float*)d_in[4];
    const float* W3  = (const float*)d_in[5];
    const float* b3  = (const float*)d_in[6];
    const float* Wm  = (const float*)d_in[7];
    const float* bm  = (const float*)d_in[8];
    const float* Wf1 = (const float*)d_in[9];
    const float* bf1 = (const float*)d_in[10];
    const float* Wf2 = (const float*)d_in[11];
    const float* bf2 = (const float*)d_in[12];
    const int* locs  = (const int*)d_in[13];
    float* out = (float*)d_out;

    float* ws = (float*)d_ws;
    size_t o = 0;
    float* P1[2]; P1[0] = ws + o; o += 2 * 75 * PPLANE;  P1[1] = ws + o; o += 2 * 75 * PPLANE;
    float* P2[2]; P2[0] = ws + o; o += 2 * 192 * PPLANE; P2[1] = ws + o; o += 2 * 192 * PPLANE;
    float* P3[2]; P3[0] = ws + o; o += 2 * 256 * PPLANE; P3[1] = ws + o; o += 2 * 256 * PPLANE;
    float* C1 = ws + o; o += 2 * 64 * 1024;
    float* C2 = ws + o; o += 2 * 128 * 1024;
    float* C3 = ws + o; o += 2 * 128 * 1024;
    float* H3 = ws + o; o += 2 * 128 * 1024;

    // Zero all state/padded buffers each call (h,c initial = 0; pad borders = 0).
    hipMemsetAsync(d_ws, 0, o * sizeof(float), stream);

    for (int t = 0; t < TX; ++t) {
        const int cur = t & 1, nxt = cur ^ 1;
        stage_x_kernel<<<dim3(88), 256, 0, stream>>>(X, P1[cur], t);
        // cell1: in [x(11)|h1(64)]  -> h1 to P1[nxt]@ch11 and P2[cur]@ch0
        cell_kernel<75, 64><<<dim3(2, 64, 2), 256, 0, stream>>>(
            P1[cur], W1, b1, C1, P1[nxt] + 11 * PPLANE, 75, P2[cur], 192, nullptr);
        // cell2: in [h1(64)|h2(128)] -> h2 to P2[nxt]@ch64 and P3[cur]@ch0
        cell_kernel<192, 128><<<dim3(2, 128, 2), 256, 0, stream>>>(
            P2[cur], W2, b2, C2, P2[nxt] + 64 * PPLANE, 192, P3[cur], 256, nullptr);
        // cell3: in [h2(128)|h3(128)] -> h3 to P3[nxt]@ch128 and plain H3
        cell_kernel<256, 128><<<dim3(2, 128, 2), 256, 0, stream>>>(
            P3[cur], W3, b3, C3, P3[nxt] + 128 * PPLANE, 256, nullptr, 0, H3);
        meo_kernel<<<dim3(4, 5, 2), 256, 0, stream>>>(H3, Wm, bm, out, t);
        aqi_kernel<<<dim3(NSTA, 2), 256, 0, stream>>>(H3, Wf1, bf1, Wf2, bf2, locs, out, t);
    }
}

// Round 3
// 1892.841 us; speedup vs baseline: 1.5138x; 1.5138x over previous
//
#include <hip/hip_runtime.h>
#include <math.h>

// Problem constants
#define TX 6
#define NB 2
#define NSTA 35
#define PPLANE 1296      // 36*36 padded plane
#define PADW 36

typedef __attribute__((ext_vector_type(8))) _Float16 half8;
typedef __attribute__((ext_vector_type(4))) float f32x4;

__device__ __forceinline__ float sigf(float x) { return 1.0f / (1.0f + __expf(-x)); }

// ---------------------------------------------------------------------------
// Weight prep: W (4CH,CTOT,5,5) fp32, gate-block-major (i,f,o,g) ->
// Wk[d=dy*5+dx][m=hc*4+gate][cin_padded] f16  (zero-padded cin)
// ---------------------------------------------------------------------------
template <int CTOT, int CTOTP, int CH>
__global__ __launch_bounds__(256) void prep_w(const float* __restrict__ W,
                                              _Float16* __restrict__ Wk) {
    const int total = 25 * 4 * CH * CTOTP;
    int i = blockIdx.x * 256 + threadIdx.x;
    if (i >= total) return;
    const int cin = i % CTOTP;
    const int m = (i / CTOTP) % (4 * CH);
    const int d = i / (CTOTP * 4 * CH);
    const int hc = m >> 2, g = m & 3;
    float v = 0.f;
    if (cin < CTOT) v = W[(((g * CH + hc) * CTOT) + cin) * 25 + d];
    Wk[i] = (_Float16)v;
}

// ---------------------------------------------------------------------------
// Stage x_t into T1[cur] channels [0,11), transposed padded layout (stride 96)
// ---------------------------------------------------------------------------
__global__ __launch_bounds__(256) void stage_x(const float* __restrict__ X,
                                               _Float16* __restrict__ T1, int t) {
    int i = blockIdx.x * 256 + threadIdx.x;   // 2*1024*16
    const int c = i & 15;
    const int pix = (i >> 4) & 1023;
    const int b = i >> 14;
    if (c >= 11 || b >= NB) return;
    const int y = pix >> 5, x = pix & 31;
    const int pp = (y + 2) * PADW + (x + 2);
    T1[((size_t)(b * PPLANE) + pp) * 96 + c] =
        (_Float16)X[(((b * TX + t) * 11 + c) << 10) + pix];
}

// ---------------------------------------------------------------------------
// MFMA ConvLSTM cell. Implicit GEMM: gates[m][n] = sum_d sum_cin Wk[d][m][cin]
//   * T[b][pp(n,d)][cin], m = hc*4+gate, n = pixel. 25 shifted GEMMs.
// Block: 256 thr = 4 waves; wave owns n-tile of 16 px; BM=32 (2 m-tiles).
// grid = (1024/64, M/32, 2).
// A-frag: lane holds Wk[d][mBase+mt*16+(lane&15)][k0+(lane>>4)*8 ..+8]
// B-frag: lane holds T[pp][k0+(lane>>4)*8 ..+8], pp from px=(lane&15 within tile)
// D: row=(lane>>4)*4+r, col=lane&15  ->  each lane's 4 regs = gates i,f,o,g of
// one hc at one pixel -> LSTM update is lane-local.
// ---------------------------------------------------------------------------
template <int CTOTP, int CH>
__global__ __launch_bounds__(256) void cell_mfma(
    const _Float16* __restrict__ T,      // (2, 1296, CTOTP)
    const _Float16* __restrict__ Wk,     // (25, 4CH, CTOTP)
    const float* __restrict__ Bias,      // (4CH) original gate-block layout
    float* __restrict__ Cst,             // (2, CH, 1024) fp32, in/out
    _Float16* __restrict__ outA, int strideA,   // pre-offset by channel base
    _Float16* __restrict__ outB, int strideB,   // optional
    float* __restrict__ outP)                   // optional plain (2,CH,1024)
{
    constexpr int M = 4 * CH;
    const int tid = threadIdx.x;
    const int wave = tid >> 6, lane = tid & 63;
    const int l16 = lane & 15, lk = lane >> 4;
    const int nBase = blockIdx.x * 64 + wave * 16;
    const int mBase = blockIdx.y * 32;
    const int b = blockIdx.z;
    const int px = nBase + l16;
    const int y = px >> 5, x = px & 31;

    const _Float16* Tb = T + (size_t)(b * PPLANE) * CTOTP + lk * 8;
    const _Float16* Wl = Wk + (size_t)(mBase + l16) * CTOTP + lk * 8;

    f32x4 acc0 = {0.f, 0.f, 0.f, 0.f};
    f32x4 acc1 = {0.f, 0.f, 0.f, 0.f};

    for (int d = 0; d < 25; ++d) {
        const int dy = d / 5, dx = d - dy * 5;
        const _Float16* tb = Tb + (size_t)((y + dy) * PADW + (x + dx)) * CTOTP;
        const _Float16* wl = Wl + (size_t)d * M * CTOTP;
#pragma unroll
        for (int kc = 0; kc < CTOTP / 32; ++kc) {
            const half8 bfrag = *(const half8*)(tb + kc * 32);
            const half8 a0 = *(const half8*)(wl + kc * 32);
            const half8 a1 = *(const half8*)(wl + 16 * CTOTP + kc * 32);
            acc0 = __builtin_amdgcn_mfma_f32_16x16x32_f16(a0, bfrag, acc0, 0, 0, 0);
            acc1 = __builtin_amdgcn_mfma_f32_16x16x32_f16(a1, bfrag, acc1, 0, 0, 0);
        }
    }

    const int hcBase = mBase >> 2;
    const int ppc = (y + 2) * PADW + (x + 2);
#pragma unroll
    for (int mt = 0; mt < 2; ++mt) {
        const f32x4 acc = mt ? acc1 : acc0;
        const int hc = hcBase + mt * 4 + lk;
        const float gi = acc[0] + Bias[hc];
        const float gf = acc[1] + Bias[CH + hc];
        const float go = acc[2] + Bias[2 * CH + hc];
        const float gg = acc[3] + Bias[3 * CH + hc];
        const int idx = ((b * CH + hc) << 10) + px;
        const float c_old = Cst[idx];
        const float cn = sigf(gf) * c_old + sigf(gi) * tanhf(gg);
        const float hn = sigf(go) * tanhf(cn);
        Cst[idx] = cn;
        const _Float16 hh = (_Float16)hn;
        outA[(size_t)(b * PPLANE + ppc) * strideA + hc] = hh;
        if (outB) outB[(size_t)(b * PPLANE + ppc) * strideB + hc] = hh;
        if (outP) outP[idx] = hn;
    }
}

// ---------------------------------------------------------------------------
// meo head: 1x1 conv 128 -> 5 on plain fp32 H3
// ---------------------------------------------------------------------------
__global__ __launch_bounds__(256) void meo_kernel(const float* __restrict__ H3,
                                                  const float* __restrict__ Wm,
                                                  const float* __restrict__ bm,
                                                  float* __restrict__ out, int t) {
    const int pix = blockIdx.x * 256 + threadIdx.x;
    const int oc = blockIdx.y, b = blockIdx.z;
    float acc = bm[oc];
    const float* w = Wm + oc * 128;
    const float* h = H3 + ((b * 128) << 10) + pix;
#pragma unroll 8
    for (int c = 0; c < 128; ++c) acc = fmaf(w[c], h[c << 10], acc);
    out[2520 + (b * TX + t) * 5120 + (oc << 10) + pix] = acc;
}

// ---------------------------------------------------------------------------
// aqi head: gather 128x3x3 patch -> MLP 1152->256->6. grid = (35, 2)
// ---------------------------------------------------------------------------
__global__ __launch_bounds__(256) void aqi_kernel(const float* __restrict__ H3,
                                                  const float* __restrict__ Wf1,
                                                  const float* __restrict__ bf1,
                                                  const float* __restrict__ Wf2,
                                                  const float* __restrict__ bf2,
                                                  const int* __restrict__ locs,
                                                  float* __restrict__ out, int t) {
    __shared__ float feats[1152];
    __shared__ float hid[256];
    const int s = blockIdx.x, b = blockIdx.y, tid = threadIdx.x;
    const int y0 = locs[2 * s], x0 = locs[2 * s + 1];
    for (int k = tid; k < 1152; k += 256) {
        const int c = k / 9, r = k % 9;
        const int i = r / 3, j = r % 3;
        feats[k] = H3[((b * 128 + c) << 10) + (y0 + i) * 32 + (x0 + j)];
    }
    __syncthreads();
    float acc = bf1[tid];
    for (int k = 0; k < 1152; ++k) acc = fmaf(feats[k], Wf1[k * 256 + tid], acc);
    hid[tid] = tanhf(acc);
    __syncthreads();
    if (tid < 6) {
        float a = bf2[tid];
        for (int k = 0; k < 256; ++k) a = fmaf(hid[k], Wf2[k * 6 + tid], a);
        out[(b * TX + t) * 210 + s * 6 + tid] = a;
    }
}

// ---------------------------------------------------------------------------
extern "C" void kernel_launch(void* const* d_in, const int* in_sizes, int n_in,
                              void* d_out, int out_size, void* d_ws, size_t ws_size,
                              hipStream_t stream) {
    const float* X   = (const float*)d_in[0];
    const float* W1  = (const float*)d_in[1];
    const float* b1  = (const float*)d_in[2];
    const float* W2  = (const float*)d_in[3];
    const float* b2  = (const float*)d_in[4];
    const float* W3  = (const float*)d_in[5];
    const float* b3  = (const float*)d_in[6];
    const float* Wm  = (const float*)d_in[7];
    const float* bm  = (const float*)d_in[8];
    const float* Wf1 = (const float*)d_in[9];
    const float* bf1 = (const float*)d_in[10];
    const float* Wf2 = (const float*)d_in[11];
    const float* bf2 = (const float*)d_in[12];
    const int* locs  = (const int*)d_in[13];
    float* out = (float*)d_out;

    // Byte-offset allocator, 256B aligned
    char* base = (char*)d_ws;
    size_t off = 0;
    auto alloc = [&](size_t bytes) -> char* {
        char* p = base + off;
        off = (off + bytes + 255) & ~(size_t)255;
        return p;
    };
    // Zeroed region: T buffers (f16), C states (fp32), H3
    _Float16* T1[2]; T1[0] = (_Float16*)alloc(2 * PPLANE * 96 * 2);
                     T1[1] = (_Float16*)alloc(2 * PPLANE * 96 * 2);
    _Float16* T2[2]; T2[0] = (_Float16*)alloc(2 * PPLANE * 192 * 2);
                     T2[1] = (_Float16*)alloc(2 * PPLANE * 192 * 2);
    _Float16* T3[2]; T3[0] = (_Float16*)alloc(2 * PPLANE * 256 * 2);
                     T3[1] = (_Float16*)alloc(2 * PPLANE * 256 * 2);
    float* C1 = (float*)alloc(2 * 64 * 1024 * 4);
    float* C2 = (float*)alloc(2 * 128 * 1024 * 4);
    float* C3 = (float*)alloc(2 * 128 * 1024 * 4);
    float* H3 = (float*)alloc(2 * 128 * 1024 * 4);
    const size_t zero_bytes = off;
    // Non-zeroed: weight buffers (fully written by prep each call)
    _Float16* Wk1 = (_Float16*)alloc((size_t)25 * 256 * 96 * 2);
    _Float16* Wk2 = (_Float16*)alloc((size_t)25 * 512 * 192 * 2);
    _Float16* Wk3 = (_Float16*)alloc((size_t)25 * 512 * 256 * 2);

    hipMemsetAsync(d_ws, 0, zero_bytes, stream);

    prep_w<75, 96, 64><<<dim3((25 * 256 * 96 + 255) / 256), 256, 0, stream>>>(W1, Wk1);
    prep_w<192, 192, 128><<<dim3((25 * 512 * 192 + 255) / 256), 256, 0, stream>>>(W2, Wk2);
    prep_w<256, 256, 128><<<dim3((25 * 512 * 256 + 255) / 256), 256, 0, stream>>>(W3, Wk3);

    for (int t = 0; t < TX; ++t) {
        const int cur = t & 1, nxt = cur ^ 1;
        stage_x<<<dim3(128), 256, 0, stream>>>(X, T1[cur], t);
        // cell1: T1[cur](96) -> h1 to T1[nxt]@11 and T2[cur]@0
        cell_mfma<96, 64><<<dim3(16, 8, 2), 256, 0, stream>>>(
            T1[cur], Wk1, b1, C1, T1[nxt] + 11, 96, T2[cur] + 0, 192, nullptr);
        // cell2: T2[cur](192) -> h2 to T2[nxt]@64 and T3[cur]@0
        cell_mfma<192, 128><<<dim3(16, 16, 2), 256, 0, stream>>>(
            T2[cur], Wk2, b2, C2, T2[nxt] + 64, 192, T3[cur] + 0, 256, nullptr);
        // cell3: T3[cur](256) -> h3 to T3[nxt]@128 and plain H3
        cell_mfma<256, 128><<<dim3(16, 16, 2), 256, 0, stream>>>(
            T3[cur], Wk3, b3, C3, T3[nxt] + 128, 256, nullptr, 0, H3);
        meo_kernel<<<dim3(4, 5, 2), 256, 0, stream>>>(H3, Wm, bm, out, t);
        aqi_kernel<<<dim3(NSTA, 2), 256, 0, stream>>>(H3, Wf1, bf1, Wf2, bf2, locs, out, t);
    }
}

// Round 5
// 1143.010 us; speedup vs baseline: 2.5068x; 1.6560x over previous
//
#include <hip/hip_runtime.h>
#include <math.h>

// Problem constants
#define TX 6
#define NB 2
#define NSTA 35
#define PPLANE 1296      // 36*36 padded plane
#define PADW 36

typedef __attribute__((ext_vector_type(8))) _Float16 half8;
typedef __attribute__((ext_vector_type(4))) float f32x4;

__device__ __forceinline__ float sigf(float x) { return 1.0f / (1.0f + __expf(-x)); }

// ---------------------------------------------------------------------------
// Weight prep: W (4CH,CTOT,5,5) fp32 gate-block-major ->
// Wk[d][mb][c32][lk][l16][e8] f16 : fragment = 512 f16 (16 m-rows x 32 cin).
// m = mb*16+l16 (= hc*4+gate), cin = c32*32+lk*8+e.
// ---------------------------------------------------------------------------
template <int CTOT, int CTOTP, int CH>
__global__ __launch_bounds__(256) void prep_w2(const float* __restrict__ W,
                                               _Float16* __restrict__ Wk) {
    constexpr int M = 4 * CH;
    const int total = 25 * M * CTOTP;
    int i = blockIdx.x * 256 + threadIdx.x;
    if (i >= total) return;
    const int e   = i & 7;
    const int l16 = (i >> 3) & 15;
    const int lk  = (i >> 7) & 3;
    const int c32 = (i >> 9) % (CTOTP / 32);
    const int rest = (i >> 9) / (CTOTP / 32);
    const int mb = rest % (M / 16);
    const int d  = rest / (M / 16);
    const int m = mb * 16 + l16;
    const int cin = c32 * 32 + lk * 8 + e;
    const int hc = m >> 2, g = m & 3;
    float v = 0.f;
    if (cin < CTOT) v = W[((g * CH + hc) * CTOT + cin) * 25 + d];
    Wk[i] = (_Float16)v;
}

// ---------------------------------------------------------------------------
// Stage x_t into T1[cur] channels [0,11), transposed padded layout (stride 96)
// ---------------------------------------------------------------------------
__global__ __launch_bounds__(256) void stage_x(const float* __restrict__ X,
                                               _Float16* __restrict__ T1, int t) {
    int i = blockIdx.x * 256 + threadIdx.x;   // 2*1024*16
    const int c = i & 15;
    const int pix = (i >> 4) & 1023;
    const int b = i >> 14;
    if (c >= 11 || b >= NB) return;
    const int y = pix >> 5, x = pix & 31;
    const int pp = (y + 2) * PADW + (x + 2);
    T1[((size_t)(b * PPLANE) + pp) * 96 + c] =
        (_Float16)X[(((b * TX + t) * 11 + c) << 10) + pix];
}

// ---------------------------------------------------------------------------
// MFMA ConvLSTM cell, LDS-staged implicit GEMM.
// GEMM: gates[M][N], M = 4*CH (m = hc*4+gate), N = 2048 (batch folded), K = 25*CTOTP.
// Block: 64m x 64n (2 pixel rows), 4 waves (2wm x 2wn), wave = 32m x 32n, acc 2x2.
// Per cin-chunk of 32: stage slab[rr(6)][c8(4)][col(36)][8cin] in LDS (13.8 KB),
// reuse across all 25 taps. B-read: lane stride 16B -> each 16-lane phase reads
// 256B contiguous = conflict-free; tap offset is a compile-time immediate.
// A streamed from global: 1KB coalesced fragment reads, L2-resident via XCD mapping
// (mtile = bid % NM; NM=8 matches 8-XCD round-robin for cells 2/3).
// grid = NM * 32.
// ---------------------------------------------------------------------------
template <int CTOTP, int CH, int NM>
__global__ __launch_bounds__(256) void cell_mfma2(
    const _Float16* __restrict__ T,      // (2, 1296, CTOTP)
    const _Float16* __restrict__ Wk,     // chunked layout, see prep_w2
    const float* __restrict__ Bias,      // (4CH) gate-block layout
    float* __restrict__ Cst,             // (2, CH, 1024) fp32, in/out
    _Float16* __restrict__ outA, int strideA,   // pre-offset by channel base
    _Float16* __restrict__ outB, int strideB,   // optional
    float* __restrict__ outP)                   // optional plain (2,CH,1024)
{
    constexpr int M = 4 * CH;
    constexpr int NCH = CTOTP / 32;
    __shared__ _Float16 slab[6 * 4 * 36 * 8];   // 13824 B

    const int tid = threadIdx.x;
    const int wave = tid >> 6, lane = tid & 63;
    const int l16 = lane & 15, lk = lane >> 4;
    const int wm = wave >> 1, wn = wave & 1;
    const int bid = blockIdx.x;
    const int mtile = bid % NM;            // 64-row m tile
    const int ntile = bid / NM;            // 64-pixel n tile
    const int nbase = ntile * 64;
    const int b = nbase >> 10;
    const int y0 = (nbase & 1023) >> 5;    // first pixel row (even)
    const _Float16* Tb = T + (size_t)(b * PPLANE) * CTOTP;
    half8* s8 = (half8*)slab;

    f32x4 acc[2][2] = {};

    // B base byte offsets: slab[r+dy][lk][x+dx] -> bbase + (dy*144+dx)*16
    int bbase[2];
#pragma unroll
    for (int nt = 0; nt < 2; ++nt) {
        const int pxl = wn * 32 + nt * 16 + l16;
        const int r = pxl >> 5, x = pxl & 31;
        bbase[nt] = (((r * 4 + lk) * 36) + x) * 16;
    }
    const int laneAoff = lk * 128 + l16 * 8;   // element offset within 512-frag

    for (int c32 = 0; c32 < NCH; ++c32) {
        __syncthreads();
        // stage slab: rows y0..y0+5, all 36 cols, cin chunk [c32*32, +32)
        for (int idx = tid; idx < 864; idx += 256) {
            const int c8 = idx & 3;
            const int cr = idx >> 2;             // 0..215
            const int col = cr % 36, rr = cr / 36;
            s8[(rr * 4 + c8) * 36 + col] = *(const half8*)(Tb +
                (size_t)((y0 + rr) * PADW + col) * CTOTP + c32 * 32 + c8 * 8);
        }
        __syncthreads();
#pragma unroll
        for (int d = 0; d < 25; ++d) {
            const int dy = d / 5, dx = d - dy * 5;
            const int boff = (dy * 144 + dx) * 16;
            half8 bfrag[2], afrag[2];
#pragma unroll
            for (int nt = 0; nt < 2; ++nt)
                bfrag[nt] = *(const half8*)((const char*)slab + bbase[nt] + boff);
#pragma unroll
            for (int mt = 0; mt < 2; ++mt) {
                const int mb = mtile * 4 + wm * 2 + mt;
                afrag[mt] = *(const half8*)(Wk +
                    (size_t)(((d * (M / 16) + mb) * NCH + c32) * 512 + laneAoff));
            }
#pragma unroll
            for (int mt = 0; mt < 2; ++mt)
#pragma unroll
                for (int nt = 0; nt < 2; ++nt)
                    acc[mt][nt] = __builtin_amdgcn_mfma_f32_16x16x32_f16(
                        afrag[mt], bfrag[nt], acc[mt][nt], 0, 0, 0);
        }
    }

    // Epilogue: lane-local LSTM update. D row = lk*4 + r -> gates i,f,o,g of one hc.
#pragma unroll
    for (int mt = 0; mt < 2; ++mt) {
        const int hc = mtile * 16 + wm * 8 + mt * 4 + lk;
        const float bi = Bias[hc], bf = Bias[CH + hc];
        const float bo = Bias[2 * CH + hc], bg = Bias[3 * CH + hc];
#pragma unroll
        for (int nt = 0; nt < 2; ++nt) {
            const int pxl = wn * 32 + nt * 16 + l16;
            const int pix = (nbase & 1023) + pxl;
            const int y = pix >> 5, x = pix & 31;
            const f32x4 a = acc[mt][nt];
            const float gi = a[0] + bi, gf = a[1] + bf;
            const float go = a[2] + bo, gg = a[3] + bg;
            const int idx = ((b * CH + hc) << 10) + pix;
            const float c_old = Cst[idx];
            const float cn = sigf(gf) * c_old + sigf(gi) * tanhf(gg);
            const float hn = sigf(go) * tanhf(cn);
            Cst[idx] = cn;
            const _Float16 hh = (_Float16)hn;
            const size_t pp = (size_t)(b * PPLANE) + (y + 2) * PADW + (x + 2);
            outA[pp * strideA + hc] = hh;
            if (outB) outB[pp * strideB + hc] = hh;
            if (outP) outP[idx] = hn;
        }
    }
}

// ---------------------------------------------------------------------------
// meo head: 1x1 conv 128 -> 5 on plain fp32 H3
// ---------------------------------------------------------------------------
__global__ __launch_bounds__(256) void meo_kernel(const float* __restrict__ H3,
                                                  const float* __restrict__ Wm,
                                                  const float* __restrict__ bm,
                                                  float* __restrict__ out, int t) {
    const int pix = blockIdx.x * 256 + threadIdx.x;
    const int oc = blockIdx.y, b = blockIdx.z;
    float acc = bm[oc];
    const float* w = Wm + oc * 128;
    const float* h = H3 + ((b * 128) << 10) + pix;
#pragma unroll 8
    for (int c = 0; c < 128; ++c) acc = fmaf(w[c], h[c << 10], acc);
    out[2520 + (b * TX + t) * 5120 + (oc << 10) + pix] = acc;
}

// ---------------------------------------------------------------------------
// aqi head: gather 128x3x3 patch -> MLP 1152->256->6. grid = (35, 2)
// ---------------------------------------------------------------------------
__global__ __launch_bounds__(256) void aqi_kernel(const float* __restrict__ H3,
                                                  const float* __restrict__ Wf1,
                                                  const float* __restrict__ bf1,
                                                  const float* __restrict__ Wf2,
                                                  const float* __restrict__ bf2,
                                                  const int* __restrict__ locs,
                                                  float* __restrict__ out, int t) {
    __shared__ float feats[1152];
    __shared__ float hid[256];
    const int s = blockIdx.x, b = blockIdx.y, tid = threadIdx.x;
    const int y0 = locs[2 * s], x0 = locs[2 * s + 1];
    for (int k = tid; k < 1152; k += 256) {
        const int c = k / 9, r = k % 9;
        const int i = r / 3, j = r % 3;
        feats[k] = H3[((b * 128 + c) << 10) + (y0 + i) * 32 + (x0 + j)];
    }
    __syncthreads();
    float acc = bf1[tid];
    for (int k = 0; k < 1152; ++k) acc = fmaf(feats[k], Wf1[k * 256 + tid], acc);
    hid[tid] = tanhf(acc);
    __syncthreads();
    if (tid < 6) {
        float a = bf2[tid];
        for (int k = 0; k < 256; ++k) a = fmaf(hid[k], Wf2[k * 6 + tid], a);
        out[(b * TX + t) * 210 + s * 6 + tid] = a;
    }
}

// ---------------------------------------------------------------------------
extern "C" void kernel_launch(void* const* d_in, const int* in_sizes, int n_in,
                              void* d_out, int out_size, void* d_ws, size_t ws_size,
                              hipStream_t stream) {
    const float* X   = (const float*)d_in[0];
    const float* W1  = (const float*)d_in[1];
    const float* b1  = (const float*)d_in[2];
    const float* W2  = (const float*)d_in[3];
    const float* b2  = (const float*)d_in[4];
    const float* W3  = (const float*)d_in[5];
    const float* b3  = (const float*)d_in[6];
    const float* Wm  = (const float*)d_in[7];
    const float* bm  = (const float*)d_in[8];
    const float* Wf1 = (const float*)d_in[9];
    const float* bf1 = (const float*)d_in[10];
    const float* Wf2 = (const float*)d_in[11];
    const float* bf2 = (const float*)d_in[12];
    const int* locs  = (const int*)d_in[13];
    float* out = (float*)d_out;

    // Byte-offset allocator, 256B aligned
    char* base = (char*)d_ws;
    size_t off = 0;
    auto alloc = [&](size_t bytes) -> char* {
        char* p = base + off;
        off = (off + bytes + 255) & ~(size_t)255;
        return p;
    };
    // Zeroed region: T buffers (f16), C states (fp32), H3
    _Float16* T1[2]; T1[0] = (_Float16*)alloc(2 * PPLANE * 96 * 2);
                     T1[1] = (_Float16*)alloc(2 * PPLANE * 96 * 2);
    _Float16* T2[2]; T2[0] = (_Float16*)alloc(2 * PPLANE * 192 * 2);
                     T2[1] = (_Float16*)alloc(2 * PPLANE * 192 * 2);
    _Float16* T3[2]; T3[0] = (_Float16*)alloc(2 * PPLANE * 256 * 2);
                     T3[1] = (_Float16*)alloc(2 * PPLANE * 256 * 2);
    float* C1 = (float*)alloc(2 * 64 * 1024 * 4);
    float* C2 = (float*)alloc(2 * 128 * 1024 * 4);
    float* C3 = (float*)alloc(2 * 128 * 1024 * 4);
    float* H3 = (float*)alloc(2 * 128 * 1024 * 4);
    const size_t zero_bytes = off;
    // Non-zeroed: weight buffers (fully written by prep each call)
    _Float16* Wk1 = (_Float16*)alloc((size_t)25 * 256 * 96 * 2);
    _Float16* Wk2 = (_Float16*)alloc((size_t)25 * 512 * 192 * 2);
    _Float16* Wk3 = (_Float16*)alloc((size_t)25 * 512 * 256 * 2);

    hipMemsetAsync(d_ws, 0, zero_bytes, stream);

    prep_w2<75, 96, 64><<<dim3((25 * 256 * 96 + 255) / 256), 256, 0, stream>>>(W1, Wk1);
    prep_w2<192, 192, 128><<<dim3((25 * 512 * 192 + 255) / 256), 256, 0, stream>>>(W2, Wk2);
    prep_w2<256, 256, 128><<<dim3((25 * 512 * 256 + 255) / 256), 256, 0, stream>>>(W3, Wk3);

    for (int t = 0; t < TX; ++t) {
        const int cur = t & 1, nxt = cur ^ 1;
        stage_x<<<dim3(128), 256, 0, stream>>>(X, T1[cur], t);
        // cell1: T1[cur](96) -> h1 to T1[nxt]@11 and T2[cur]@0   (M=256 -> NM=4)
        cell_mfma2<96, 64, 4><<<dim3(4 * 32), 256, 0, stream>>>(
            T1[cur], Wk1, b1, C1, T1[nxt] + 11, 96, T2[cur] + 0, 192, nullptr);
        // cell2: T2[cur](192) -> h2 to T2[nxt]@64 and T3[cur]@0  (M=512 -> NM=8)
        cell_mfma2<192, 128, 8><<<dim3(8 * 32), 256, 0, stream>>>(
            T2[cur], Wk2, b2, C2, T2[nxt] + 64, 192, T3[cur] + 0, 256, nullptr);
        // cell3: T3[cur](256) -> h3 to T3[nxt]@128 and plain H3
        cell_mfma2<256, 128, 8><<<dim3(8 * 32), 256, 0, stream>>>(
            T3[cur], Wk3, b3, C3, T3[nxt] + 128, 256, nullptr, 0, H3);
        meo_kernel<<<dim3(4, 5, 2), 256, 0, stream>>>(H3, Wm, bm, out, t);
        aqi_kernel<<<dim3(NSTA, 2), 256, 0, stream>>>(H3, Wf1, bf1, Wf2, bf2, locs, out, t);
    }
}

// Round 7
// 1121.410 us; speedup vs baseline: 2.5551x; 1.0193x over previous
//
#include <hip/hip_runtime.h>
#include <math.h>

// Problem constants
#define TX 6
#define NB 2
#define NSTA 35
#define PPLANE 1296      // 36*36 padded plane
#define PADW 36

typedef __attribute__((ext_vector_type(8))) _Float16 half8;
typedef __attribute__((ext_vector_type(4))) float f32x4;

__device__ __forceinline__ float sigf(float x) { return 1.0f / (1.0f + __expf(-x)); }

// Async global->LDS DMA, 16B per lane. LDS dest is wave-uniform base + lane*16.
__device__ __forceinline__ void gload_lds16(const void* g, void* l) {
    __builtin_amdgcn_global_load_lds(
        (const __attribute__((address_space(1))) void*)g,
        (__attribute__((address_space(3))) void*)l, 16, 0, 0);
}

// ---------------------------------------------------------------------------
// Weight prep: W (4CH,CTOT,5,5) fp32 gate-block-major ->
// Wk[d][mb][c32][lk][l16][e8] f16 : fragment = 512 f16 (16 m-rows x 32 cin).
// m = mb*16+l16 (= hc*4+gate), cin = c32*32+lk*8+e.
// ---------------------------------------------------------------------------
template <int CTOT, int CTOTP, int CH>
__global__ __launch_bounds__(256) void prep_w2(const float* __restrict__ W,
                                               _Float16* __restrict__ Wk) {
    constexpr int M = 4 * CH;
    const int total = 25 * M * CTOTP;
    int i = blockIdx.x * 256 + threadIdx.x;
    if (i >= total) return;
    const int e   = i & 7;
    const int l16 = (i >> 3) & 15;
    const int lk  = (i >> 7) & 3;
    const int c32 = (i >> 9) % (CTOTP / 32);
    const int rest = (i >> 9) / (CTOTP / 32);
    const int mb = rest % (M / 16);
    const int d  = rest / (M / 16);
    const int m = mb * 16 + l16;
    const int cin = c32 * 32 + lk * 8 + e;
    const int hc = m >> 2, g = m & 3;
    float v = 0.f;
    if (cin < CTOT) v = W[((g * CH + hc) * CTOT + cin) * 25 + d];
    Wk[i] = (_Float16)v;
}

// ---------------------------------------------------------------------------
// Stage x_t into T1[cur] channels [0,11), transposed padded layout (stride 96)
// ---------------------------------------------------------------------------
__global__ __launch_bounds__(256) void stage_x(const float* __restrict__ X,
                                               _Float16* __restrict__ T1, int t) {
    int i = blockIdx.x * 256 + threadIdx.x;   // 2*1024*16
    const int c = i & 15;
    const int pix = (i >> 4) & 1023;
    const int b = i >> 14;
    if (c >= 11 || b >= NB) return;
    const int y = pix >> 5, x = pix & 31;
    const int pp = (y + 2) * PADW + (x + 2);
    T1[((size_t)(b * PPLANE) + pp) * 96 + c] =
        (_Float16)X[(((b * TX + t) * 11 + c) << 10) + pix];
}

// ---------------------------------------------------------------------------
// MFMA ConvLSTM cell, double-buffered global_load_lds-staged implicit GEMM.
// GEMM: gates[M][N], M = 4*CH (m = hc*4+gate), N = 2048, K = 25*CTOTP.
// Block: 64m x 64n (2 pixel rows), 4 waves (2wm x 2wn), wave 32x32, acc 2x2.
// LDS slab layout (slot = 16B): slot = (rr*4 + c8)*36 + col  ([row][cin8][col]).
// DMA staging is linear (slot = idx), so the stage decode is the layout
// inverse: col = idx%36, rc = idx/36, c8 = rc&3, rr = rc>>2.   <-- r6 bugfix
// Double-buffered: stage chunk c+1 while computing chunk c; __syncthreads()'s
// vmcnt drain is the pipeline wait (m97 pattern).
// B-read: lane stride 16B -> conflict-free; tap offset = compile-time immediate.
// A streamed from global (L2-resident; mtile = bid % NM maps to XCD round-robin).
// grid = NM * 32.
// ---------------------------------------------------------------------------
template <int CTOTP, int CH, int NM>
__global__ __launch_bounds__(256) void cell_mfma3(
    const _Float16* __restrict__ T,      // (2, 1296, CTOTP)
    const _Float16* __restrict__ Wk,     // chunked layout, see prep_w2
    const float* __restrict__ Bias,     // (4CH) gate-block layout
    float* __restrict__ Cst,            // (2, CH, 1024) fp32, in/out
    _Float16* __restrict__ outA, int strideA,   // pre-offset by channel base
    _Float16* __restrict__ outB, int strideB,   // optional
    float* __restrict__ outP)                   // optional plain (2,CH,1024)
{
    constexpr int M = 4 * CH;
    constexpr int NCH = CTOTP / 32;
    // 2 buffers x 896 slots x 16B = 28672 B (864 real slots + 32 pad)
    __shared__ _Float16 slab[2 * 896 * 8];

    const int tid = threadIdx.x;
    const int wave = tid >> 6, lane = tid & 63;
    const int l16 = lane & 15, lk = lane >> 4;
    const int wm = wave >> 1, wn = wave & 1;
    const int bid = blockIdx.x;
    const int mtile = bid % NM;            // 64-row m tile
    const int ntile = bid / NM;            // 64-pixel n tile
    const int nbase = ntile * 64;
    const int b = nbase >> 10;
    const int y0 = (nbase & 1023) >> 5;    // first pixel row (even)
    const _Float16* Tb = T + (size_t)(b * PPLANE) * CTOTP;

    f32x4 acc[2][2] = {};

    // B base byte offsets: slab[r+dy][lk][x+dx] -> bbase + (dy*144+dx)*16
    int bbase[2];
#pragma unroll
    for (int nt = 0; nt < 2; ++nt) {
        const int pxl = wn * 32 + nt * 16 + l16;
        const int r = pxl >> 5, x = pxl & 31;
        bbase[nt] = (((r * 4 + lk) * 36) + x) * 16;
    }
    const int laneAoff = lk * 128 + l16 * 8;   // element offset within 512-frag

    // Stage chunk c32 into buf[c32&1]: 14 wave-segments of 64 consecutive slots.
    // Wave handles segments s = wave + 4k (wave-uniform predicate).
    // Slot idx -> (rr,c8,col) must invert slot = (rr*4+c8)*36 + col.
    auto stage = [&](int c32) {
        char* dst = (char*)slab + (c32 & 1) * 14336;
#pragma unroll
        for (int k = 0; k < 4; ++k) {
            const int s = wave + k * 4;
            if (s < 14) {
                const int idx = (s << 6) + lane;
                const int col = idx % 36;
                const int rc  = idx / 36;          // rr*4 + c8 (rc=24: pad, unread)
                const int c8 = rc & 3, rr = rc >> 2;
                const _Float16* src = Tb +
                    (size_t)((y0 + rr) * PADW + col) * CTOTP + c32 * 32 + c8 * 8;
                gload_lds16(src, dst + idx * 16);
            }
        }
    };

    stage(0);
    __syncthreads();                        // drains vmcnt before first compute

    for (int c32 = 0; c32 < NCH; ++c32) {
        if (c32 + 1 < NCH) stage(c32 + 1);  // async DMA into other buffer
        const char* sb = (const char*)slab + (c32 & 1) * 14336;
#pragma unroll
        for (int d = 0; d < 25; ++d) {
            const int dy = d / 5, dx = d - dy * 5;
            const int boff = (dy * 144 + dx) * 16;
            half8 bfrag[2], afrag[2];
#pragma unroll
            for (int nt = 0; nt < 2; ++nt)
                bfrag[nt] = *(const half8*)(sb + bbase[nt] + boff);
#pragma unroll
            for (int mt = 0; mt < 2; ++mt) {
                const int mb = mtile * 4 + wm * 2 + mt;
                afrag[mt] = *(const half8*)(Wk +
                    (size_t)(((d * (M / 16) + mb) * NCH + c32) * 512 + laneAoff));
            }
#pragma unroll
            for (int mt = 0; mt < 2; ++mt)
#pragma unroll
                for (int nt = 0; nt < 2; ++nt)
                    acc[mt][nt] = __builtin_amdgcn_mfma_f32_16x16x32_f16(
                        afrag[mt], bfrag[nt], acc[mt][nt], 0, 0, 0);
        }
        __syncthreads();   // waits compute ds_reads AND in-flight stage DMA
    }

    // Epilogue: lane-local LSTM update. D row = lk*4 + r -> gates i,f,o,g of one hc.
#pragma unroll
    for (int mt = 0; mt < 2; ++mt) {
        const int hc = mtile * 16 + wm * 8 + mt * 4 + lk;
        const float bi = Bias[hc], bf = Bias[CH + hc];
        const float bo = Bias[2 * CH + hc], bg = Bias[3 * CH + hc];
#pragma unroll
        for (int nt = 0; nt < 2; ++nt) {
            const int pxl = wn * 32 + nt * 16 + l16;
            const int pix = (nbase & 1023) + pxl;
            const int y = pix >> 5, x = pix & 31;
            const f32x4 a = acc[mt][nt];
            const float gi = a[0] + bi, gf = a[1] + bf;
            const float go = a[2] + bo, gg = a[3] + bg;
            const int idx = ((b * CH + hc) << 10) + pix;
            const float c_old = Cst[idx];
            const float cn = sigf(gf) * c_old + sigf(gi) * tanhf(gg);
            const float hn = sigf(go) * tanhf(cn);
            Cst[idx] = cn;
            const _Float16 hh = (_Float16)hn;
            const size_t pp = (size_t)(b * PPLANE) + (y + 2) * PADW + (x + 2);
            outA[pp * strideA + hc] = hh;
            if (outB) outB[pp * strideB + hc] = hh;
            if (outP) outP[idx] = hn;
        }
    }
}

// ---------------------------------------------------------------------------
// meo head: 1x1 conv 128 -> 5 on plain fp32 H3
// ---------------------------------------------------------------------------
__global__ __launch_bounds__(256) void meo_kernel(const float* __restrict__ H3,
                                                  const float* __restrict__ Wm,
                                                  const float* __restrict__ bm,
                                                  float* __restrict__ out, int t) {
    const int pix = blockIdx.x * 256 + threadIdx.x;
    const int oc = blockIdx.y, b = blockIdx.z;
    float acc = bm[oc];
    const float* w = Wm + oc * 128;
    const float* h = H3 + ((b * 128) << 10) + pix;
#pragma unroll 8
    for (int c = 0; c < 128; ++c) acc = fmaf(w[c], h[c << 10], acc);
    out[2520 + (b * TX + t) * 5120 + (oc << 10) + pix] = acc;
}

// ---------------------------------------------------------------------------
// aqi head: gather 128x3x3 patch -> MLP 1152->256->6. grid = (35, 2)
// ---------------------------------------------------------------------------
__global__ __launch_bounds__(256) void aqi_kernel(const float* __restrict__ H3,
                                                  const float* __restrict__ Wf1,
                                                  const float* __restrict__ bf1,
                                                  const float* __restrict__ Wf2,
                                                  const float* __restrict__ bf2,
                                                  const int* __restrict__ locs,
                                                  float* __restrict__ out, int t) {
    __shared__ float feats[1152];
    __shared__ float hid[256];
    const int s = blockIdx.x, b = blockIdx.y, tid = threadIdx.x;
    const int y0 = locs[2 * s], x0 = locs[2 * s + 1];
    for (int k = tid; k < 1152; k += 256) {
        const int c = k / 9, r = k % 9;
        const int i = r / 3, j = r % 3;
        feats[k] = H3[((b * 128 + c) << 10) + (y0 + i) * 32 + (x0 + j)];
    }
    __syncthreads();
    float acc = bf1[tid];
    for (int k = 0; k < 1152; ++k) acc = fmaf(feats[k], Wf1[k * 256 + tid], acc);
    hid[tid] = tanhf(acc);
    __syncthreads();
    if (tid < 6) {
        float a = bf2[tid];
        for (int k = 0; k < 256; ++k) a = fmaf(hid[k], Wf2[k * 6 + tid], a);
        out[(b * TX + t) * 210 + s * 6 + tid] = a;
    }
}

// ---------------------------------------------------------------------------
extern "C" void kernel_launch(void* const* d_in, const int* in_sizes, int n_in,
                              void* d_out, int out_size, void* d_ws, size_t ws_size,
                              hipStream_t stream) {
    const float* X   = (const float*)d_in[0];
    const float* W1  = (const float*)d_in[1];
    const float* b1  = (const float*)d_in[2];
    const float* W2  = (const float*)d_in[3];
    const float* b2  = (const float*)d_in[4];
    const float* W3  = (const float*)d_in[5];
    const float* b3  = (const float*)d_in[6];
    const float* Wm  = (const float*)d_in[7];
    const float* bm  = (const float*)d_in[8];
    const float* Wf1 = (const float*)d_in[9];
    const float* bf1 = (const float*)d_in[10];
    const float* Wf2 = (const float*)d_in[11];
    const float* bf2 = (const float*)d_in[12];
    const int* locs  = (const int*)d_in[13];
    float* out = (float*)d_out;

    // Byte-offset allocator, 256B aligned
    char* base = (char*)d_ws;
    size_t off = 0;
    auto alloc = [&](size_t bytes) -> char* {
        char* p = base + off;
        off = (off + bytes + 255) & ~(size_t)255;
        return p;
    };
    // Zeroed region: T buffers (f16), C states (fp32), H3
    _Float16* T1[2]; T1[0] = (_Float16*)alloc(2 * PPLANE * 96 * 2);
                     T1[1] = (_Float16*)alloc(2 * PPLANE * 96 * 2);
    _Float16* T2[2]; T2[0] = (_Float16*)alloc(2 * PPLANE * 192 * 2);
                     T2[1] = (_Float16*)alloc(2 * PPLANE * 192 * 2);
    _Float16* T3[2]; T3[0] = (_Float16*)alloc(2 * PPLANE * 256 * 2);
                     T3[1] = (_Float16*)alloc(2 * PPLANE * 256 * 2);
    float* C1 = (float*)alloc(2 * 64 * 1024 * 4);
    float* C2 = (float*)alloc(2 * 128 * 1024 * 4);
    float* C3 = (float*)alloc(2 * 128 * 1024 * 4);
    float* H3 = (float*)alloc(2 * 128 * 1024 * 4);
    const size_t zero_bytes = off;
    // Non-zeroed: weight buffers (fully written by prep each call)
    _Float16* Wk1 = (_Float16*)alloc((size_t)25 * 256 * 96 * 2);
    _Float16* Wk2 = (_Float16*)alloc((size_t)25 * 512 * 192 * 2);
    _Float16* Wk3 = (_Float16*)alloc((size_t)25 * 512 * 256 * 2);

    hipMemsetAsync(d_ws, 0, zero_bytes, stream);

    prep_w2<75, 96, 64><<<dim3((25 * 256 * 96 + 255) / 256), 256, 0, stream>>>(W1, Wk1);
    prep_w2<192, 192, 128><<<dim3((25 * 512 * 192 + 255) / 256), 256, 0, stream>>>(W2, Wk2);
    prep_w2<256, 256, 128><<<dim3((25 * 512 * 256 + 255) / 256), 256, 0, stream>>>(W3, Wk3);

    for (int t = 0; t < TX; ++t) {
        const int cur = t & 1, nxt = cur ^ 1;
        stage_x<<<dim3(128), 256, 0, stream>>>(X, T1[cur], t);
        // cell1: T1[cur](96) -> h1 to T1[nxt]@11 and T2[cur]@0   (M=256 -> NM=4)
        cell_mfma3<96, 64, 4><<<dim3(4 * 32), 256, 0, stream>>>(
            T1[cur], Wk1, b1, C1, T1[nxt] + 11, 96, T2[cur] + 0, 192, nullptr);
        // cell2: T2[cur](192) -> h2 to T2[nxt]@64 and T3[cur]@0  (M=512 -> NM=8)
        cell_mfma3<192, 128, 8><<<dim3(8 * 32), 256, 0, stream>>>(
            T2[cur], Wk2, b2, C2, T2[nxt] + 64, 192, T3[cur] + 0, 256, nullptr);
        // cell3: T3[cur](256) -> h3 to T3[nxt]@128 and plain H3
        cell_mfma3<256, 128, 8><<<dim3(8 * 32), 256, 0, stream>>>(
            T3[cur], Wk3, b3, C3, T3[nxt] + 128, 256, nullptr, 0, H3);
        meo_kernel<<<dim3(4, 5, 2), 256, 0, stream>>>(H3, Wm, bm, out, t);
        aqi_kernel<<<dim3(NSTA, 2), 256, 0, stream>>>(H3, Wf1, bf1, Wf2, bf2, locs, out, t);
    }
}

// Round 9
// 705.795 us; speedup vs baseline: 4.0597x; 1.5889x over previous
//
#include <hip/hip_runtime.h>
#include <math.h>

// Problem constants
#define TX 6
#define NB 2
#define NSTA 35
#define PPLANE 1296      // 36*36 padded plane
#define PADW 36

typedef __attribute__((ext_vector_type(8))) _Float16 half8;
typedef __attribute__((ext_vector_type(4))) float f32x4;

__device__ __forceinline__ float sigf(float x) { return 1.0f / (1.0f + __expf(-x)); }

// Async global->LDS DMA, 16B per lane. LDS dest is wave-uniform base + lane*16.
__device__ __forceinline__ void gload_lds16(const void* g, void* l) {
    __builtin_amdgcn_global_load_lds(
        (const __attribute__((address_space(1))) void*)g,
        (__attribute__((address_space(3))) void*)l, 16, 0, 0);
}

// ---------------------------------------------------------------------------
// Weight prep: W (4CH,CTOT,5,5) fp32 gate-block-major ->
// Wk[d][mb][c32][lk][l16][e8] f16 : fragment = 512 f16 (16 m-rows x 32 cin).
// m = mb*16+l16 (= hc*4+gate), cin = c32*32+lk*8+e.
// ---------------------------------------------------------------------------
template <int CTOT, int CTOTP, int CH>
__global__ __launch_bounds__(256) void prep_w2(const float* __restrict__ W,
                                               _Float16* __restrict__ Wk) {
    constexpr int M = 4 * CH;
    const int total = 25 * M * CTOTP;
    int i = blockIdx.x * 256 + threadIdx.x;
    if (i >= total) return;
    const int e   = i & 7;
    const int l16 = (i >> 3) & 15;
    const int lk  = (i >> 7) & 3;
    const int c32 = (i >> 9) % (CTOTP / 32);
    const int rest = (i >> 9) / (CTOTP / 32);
    const int mb = rest % (M / 16);
    const int d  = rest / (M / 16);
    const int m = mb * 16 + l16;
    const int cin = c32 * 32 + lk * 8 + e;
    const int hc = m >> 2, g = m & 3;
    float v = 0.f;
    if (cin < CTOT) v = W[((g * CH + hc) * CTOT + cin) * 25 + d];
    Wk[i] = (_Float16)v;
}

// ---------------------------------------------------------------------------
// Stage x_t into T1[cur] channels [0,11), transposed padded layout (stride 96)
// ---------------------------------------------------------------------------
__global__ __launch_bounds__(256) void stage_x(const float* __restrict__ X,
                                               _Float16* __restrict__ T1, int t) {
    int i = blockIdx.x * 256 + threadIdx.x;   // 2*1024*16
    const int c = i & 15;
    const int pix = (i >> 4) & 1023;
    const int b = i >> 14;
    if (c >= 11 || b >= NB) return;
    const int y = pix >> 5, x = pix & 31;
    const int pp = (y + 2) * PADW + (x + 2);
    T1[((size_t)(b * PPLANE) + pp) * 96 + c] =
        (_Float16)X[(((b * TX + t) * 11 + c) << 10) + pix];
}

// ---------------------------------------------------------------------------
// MFMA ConvLSTM cell v5: DMA-staged B (double-buffered) + register
// software-pipelined A and B.
// A pipeline: depth PDA=5 taps, ring slot = d % 5. 25 % 5 == 0, so the ring
// stays aligned across chunk boundaries (r8 bug: PDA=8 shifted slots by one
// per chunk since 25 % 8 != 0). Cross-chunk refills are valid: A is global,
// independent of the LDS barrier.
// B pipeline: depth 3 taps, re-prologued per chunk (no boundary crossing).
// All ring indices static under the fully-unrolled 25-tap loop (rule #20).
// GEMM: gates[M][N], M = 4*CH (m = hc*4+gate), N = 2048, K = 25*CTOTP.
// Block: 64m x 64n, 4 waves (2wm x 2wn), wave 32x32, acc 2x2.
// LDS slab (16B slots): slot = (rr*4 + c8)*36 + col; DMA decode = inverse.
// grid = NM * 32; mtile = bid % NM -> XCD round-robin keeps weights L2-local.
// ---------------------------------------------------------------------------
template <int CTOTP, int CH, int NM>
__global__ __launch_bounds__(256) void cell_mfma5(
    const _Float16* __restrict__ T,      // (2, 1296, CTOTP)
    const _Float16* __restrict__ Wk,     // chunked layout, see prep_w2
    const float* __restrict__ Bias,     // (4CH) gate-block layout
    float* __restrict__ Cst,            // (2, CH, 1024) fp32, in/out
    _Float16* __restrict__ outA, int strideA,   // pre-offset by channel base
    _Float16* __restrict__ outB, int strideB,   // optional
    float* __restrict__ outP)                   // optional plain (2,CH,1024)
{
    constexpr int M = 4 * CH;
    constexpr int NCH = CTOTP / 32;
    constexpr int PDA = 5;              // A prefetch depth; must divide 25
    // 2 buffers x 896 slots x 16B = 28672 B (864 real slots + 32 pad)
    __shared__ _Float16 slab[2 * 896 * 8];

    const int tid = threadIdx.x;
    const int wave = tid >> 6, lane = tid & 63;
    const int l16 = lane & 15, lk = lane >> 4;
    const int wm = wave >> 1, wn = wave & 1;
    const int bid = blockIdx.x;
    const int mtile = bid % NM;            // 64-row m tile
    const int ntile = bid / NM;            // 64-pixel n tile
    const int nbase = ntile * 64;
    const int b = nbase >> 10;
    const int y0 = (nbase & 1023) >> 5;    // first pixel row (even)
    const _Float16* Tb = T + (size_t)(b * PPLANE) * CTOTP;

    f32x4 acc[2][2] = {};

    // B base byte offsets: slab[r+dy][lk][x+dx] -> bbase + (dy*144+dx)*16
    int bbase[2];
#pragma unroll
    for (int nt = 0; nt < 2; ++nt) {
        const int pxl = wn * 32 + nt * 16 + l16;
        const int r = pxl >> 5, x = pxl & 31;
        bbase[nt] = (((r * 4 + lk) * 36) + x) * 16;
    }
    const int laneAoff = lk * 128 + l16 * 8;   // element offset within 512-frag

    // A-fragment load: chunk cc (runtime), tap dd (static), mt (static)
    auto loadA = [&](int cc, int dd, int mt) -> half8 {
        const int mb = mtile * 4 + wm * 2 + mt;
        return *(const half8*)(Wk +
            (size_t)(((dd * (M / 16) + mb) * NCH + cc) * 512 + laneAoff));
    };

    // Stage chunk c32 into buf[c32&1]: linear slot idx; decode inverts
    // slot = (rr*4+c8)*36 + col  (r6 bugfix decode).
    auto stage = [&](int c32) {
        char* dst = (char*)slab + (c32 & 1) * 14336;
#pragma unroll
        for (int k = 0; k < 4; ++k) {
            const int s = wave + k * 4;
            if (s < 14) {
                const int idx = (s << 6) + lane;
                const int col = idx % 36;
                const int rc  = idx / 36;          // rr*4 + c8 (rc=24: pad, unread)
                const int c8 = rc & 3, rr = rc >> 2;
                const _Float16* src = Tb +
                    (size_t)((y0 + rr) * PADW + col) * CTOTP + c32 * 32 + c8 * 8;
                gload_lds16(src, dst + idx * 16);
            }
        }
    };

    // A pipeline prologue: taps 0..PDA-1 of chunk 0
    half8 apre[PDA][2];
#pragma unroll
    for (int p = 0; p < PDA; ++p) {
        apre[p][0] = loadA(0, p, 0);
        apre[p][1] = loadA(0, p, 1);
    }

    stage(0);
    __syncthreads();                        // drains DMA (and prologue loads)

    for (int c32 = 0; c32 < NCH; ++c32) {
        if (c32 + 1 < NCH) stage(c32 + 1);  // async DMA into other buffer
        const char* sb = (const char*)slab + (c32 & 1) * 14336;

        // B pipeline prologue: taps 0..2 of this chunk
        half8 bpre[3][2];
#pragma unroll
        for (int p = 0; p < 3; ++p) {
            const int dy = p / 5, dx = p % 5;
            bpre[p][0] = *(const half8*)(sb + bbase[0] + (dy * 144 + dx) * 16);
            bpre[p][1] = *(const half8*)(sb + bbase[1] + (dy * 144 + dx) * 16);
        }

#pragma unroll
        for (int d = 0; d < 25; ++d) {
            // consume current fragments (slot = d % PDA, tap-aligned since 25%PDA==0)
            const half8 a0 = apre[d % PDA][0];
            const half8 a1 = apre[d % PDA][1];
            const half8 b0 = bpre[d % 3][0];
            const half8 b1 = bpre[d % 3][1];

            // refill A slot with tap d+PDA (slot (d+PDA)%PDA == d%PDA);
            // for d >= 25-PDA this is next chunk's tap d+PDA-25 (same slot).
            {
                const int dp = d + PDA;
                const int cstep = dp / 25;          // 0 or 1 (static)
                const int dd = dp % 25;             // static
                if (cstep == 0 || c32 + 1 < NCH) {
                    const int cc = c32 + cstep;
                    apre[d % PDA][0] = loadA(cc, dd, 0);
                    apre[d % PDA][1] = loadA(cc, dd, 1);
                }
            }
            // refill B slot with tap d+3 (within chunk)
            if (d + 3 < 25) {
                const int dy = (d + 3) / 5, dx = (d + 3) % 5;
                bpre[d % 3][0] = *(const half8*)(sb + bbase[0] + (dy * 144 + dx) * 16);
                bpre[d % 3][1] = *(const half8*)(sb + bbase[1] + (dy * 144 + dx) * 16);
            }

            acc[0][0] = __builtin_amdgcn_mfma_f32_16x16x32_f16(a0, b0, acc[0][0], 0, 0, 0);
            acc[0][1] = __builtin_amdgcn_mfma_f32_16x16x32_f16(a0, b1, acc[0][1], 0, 0, 0);
            acc[1][0] = __builtin_amdgcn_mfma_f32_16x16x32_f16(a1, b0, acc[1][0], 0, 0, 0);
            acc[1][1] = __builtin_amdgcn_mfma_f32_16x16x32_f16(a1, b1, acc[1][1], 0, 0, 0);
        }
        __syncthreads();   // waits compute ds_reads AND in-flight DMA/prefetch
    }

    // Epilogue: lane-local LSTM update. D row = lk*4 + r -> gates i,f,o,g of one hc.
#pragma unroll
    for (int mt = 0; mt < 2; ++mt) {
        const int hc = mtile * 16 + wm * 8 + mt * 4 + lk;
        const float bi = Bias[hc], bf = Bias[CH + hc];
        const float bo = Bias[2 * CH + hc], bg = Bias[3 * CH + hc];
#pragma unroll
        for (int nt = 0; nt < 2; ++nt) {
            const int pxl = wn * 32 + nt * 16 + l16;
            const int pix = (nbase & 1023) + pxl;
            const int y = pix >> 5, x = pix & 31;
            const f32x4 a = acc[mt][nt];
            const float gi = a[0] + bi, gf = a[1] + bf;
            const float go = a[2] + bo, gg = a[3] + bg;
            const int idx = ((b * CH + hc) << 10) + pix;
            const float c_old = Cst[idx];
            const float cn = sigf(gf) * c_old + sigf(gi) * tanhf(gg);
            const float hn = sigf(go) * tanhf(cn);
            Cst[idx] = cn;
            const _Float16 hh = (_Float16)hn;
            const size_t pp = (size_t)(b * PPLANE) + (y + 2) * PADW + (x + 2);
            outA[pp * strideA + hc] = hh;
            if (outB) outB[pp * strideB + hc] = hh;
            if (outP) outP[idx] = hn;
        }
    }
}

// ---------------------------------------------------------------------------
// meo head: 1x1 conv 128 -> 5 on plain fp32 H3
// ---------------------------------------------------------------------------
__global__ __launch_bounds__(256) void meo_kernel(const float* __restrict__ H3,
                                                  const float* __restrict__ Wm,
                                                  const float* __restrict__ bm,
                                                  float* __restrict__ out, int t) {
    const int pix = blockIdx.x * 256 + threadIdx.x;
    const int oc = blockIdx.y, b = blockIdx.z;
    float acc = bm[oc];
    const float* w = Wm + oc * 128;
    const float* h = H3 + ((b * 128) << 10) + pix;
#pragma unroll 8
    for (int c = 0; c < 128; ++c) acc = fmaf(w[c], h[c << 10], acc);
    out[2520 + (b * TX + t) * 5120 + (oc << 10) + pix] = acc;
}

// ---------------------------------------------------------------------------
// aqi head: gather 128x3x3 patch -> MLP 1152->256->6. grid = (35, 2)
// ---------------------------------------------------------------------------
__global__ __launch_bounds__(256) void aqi_kernel(const float* __restrict__ H3,
                                                  const float* __restrict__ Wf1,
                                                  const float* __restrict__ bf1,
                                                  const float* __restrict__ Wf2,
                                                  const float* __restrict__ bf2,
                                                  const int* __restrict__ locs,
                                                  float* __restrict__ out, int t) {
    __shared__ float feats[1152];
    __shared__ float hid[256];
    const int s = blockIdx.x, b = blockIdx.y, tid = threadIdx.x;
    const int y0 = locs[2 * s], x0 = locs[2 * s + 1];
    for (int k = tid; k < 1152; k += 256) {
        const int c = k / 9, r = k % 9;
        const int i = r / 3, j = r % 3;
        feats[k] = H3[((b * 128 + c) << 10) + (y0 + i) * 32 + (x0 + j)];
    }
    __syncthreads();
    float acc = bf1[tid];
    for (int k = 0; k < 1152; ++k) acc = fmaf(feats[k], Wf1[k * 256 + tid], acc);
    hid[tid] = tanhf(acc);
    __syncthreads();
    if (tid < 6) {
        float a = bf2[tid];
        for (int k = 0; k < 256; ++k) a = fmaf(hid[k], Wf2[k * 6 + tid], a);
        out[(b * TX + t) * 210 + s * 6 + tid] = a;
    }
}

// ---------------------------------------------------------------------------
extern "C" void kernel_launch(void* const* d_in, const int* in_sizes, int n_in,
                              void* d_out, int out_size, void* d_ws, size_t ws_size,
                              hipStream_t stream) {
    const float* X   = (const float*)d_in[0];
    const float* W1  = (const float*)d_in[1];
    const float* b1  = (const float*)d_in[2];
    const float* W2  = (const float*)d_in[3];
    const float* b2  = (const float*)d_in[4];
    const float* W3  = (const float*)d_in[5];
    const float* b3  = (const float*)d_in[6];
    const float* Wm  = (const float*)d_in[7];
    const float* bm  = (const float*)d_in[8];
    const float* Wf1 = (const float*)d_in[9];
    const float* bf1 = (const float*)d_in[10];
    const float* Wf2 = (const float*)d_in[11];
    const float* bf2 = (const float*)d_in[12];
    const int* locs  = (const int*)d_in[13];
    float* out = (float*)d_out;

    // Byte-offset allocator, 256B aligned
    char* base = (char*)d_ws;
    size_t off = 0;
    auto alloc = [&](size_t bytes) -> char* {
        char* p = base + off;
        off = (off + bytes + 255) & ~(size_t)255;
        return p;
    };
    // Zeroed region: T buffers (f16), C states (fp32), H3
    _Float16* T1[2]; T1[0] = (_Float16*)alloc(2 * PPLANE * 96 * 2);
                     T1[1] = (_Float16*)alloc(2 * PPLANE * 96 * 2);
    _Float16* T2[2]; T2[0] = (_Float16*)alloc(2 * PPLANE * 192 * 2);
                     T2[1] = (_Float16*)alloc(2 * PPLANE * 192 * 2);
    _Float16* T3[2]; T3[0] = (_Float16*)alloc(2 * PPLANE * 256 * 2);
                     T3[1] = (_Float16*)alloc(2 * PPLANE * 256 * 2);
    float* C1 = (float*)alloc(2 * 64 * 1024 * 4);
    float* C2 = (float*)alloc(2 * 128 * 1024 * 4);
    float* C3 = (float*)alloc(2 * 128 * 1024 * 4);
    float* H3 = (float*)alloc(2 * 128 * 1024 * 4);
    const size_t zero_bytes = off;
    // Non-zeroed: weight buffers (fully written by prep each call)
    _Float16* Wk1 = (_Float16*)alloc((size_t)25 * 256 * 96 * 2);
    _Float16* Wk2 = (_Float16*)alloc((size_t)25 * 512 * 192 * 2);
    _Float16* Wk3 = (_Float16*)alloc((size_t)25 * 512 * 256 * 2);

    hipMemsetAsync(d_ws, 0, zero_bytes, stream);

    prep_w2<75, 96, 64><<<dim3((25 * 256 * 96 + 255) / 256), 256, 0, stream>>>(W1, Wk1);
    prep_w2<192, 192, 128><<<dim3((25 * 512 * 192 + 255) / 256), 256, 0, stream>>>(W2, Wk2);
    prep_w2<256, 256, 128><<<dim3((25 * 512 * 256 + 255) / 256), 256, 0, stream>>>(W3, Wk3);

    for (int t = 0; t < TX; ++t) {
        const int cur = t & 1, nxt = cur ^ 1;
        stage_x<<<dim3(128), 256, 0, stream>>>(X, T1[cur], t);
        // cell1: T1[cur](96) -> h1 to T1[nxt]@11 and T2[cur]@0   (M=256 -> NM=4)
        cell_mfma5<96, 64, 4><<<dim3(4 * 32), 256, 0, stream>>>(
            T1[cur], Wk1, b1, C1, T1[nxt] + 11, 96, T2[cur] + 0, 192, nullptr);
        // cell2: T2[cur](192) -> h2 to T2[nxt]@64 and T3[cur]@0  (M=512 -> NM=8)
        cell_mfma5<192, 128, 8><<<dim3(8 * 32), 256, 0, stream>>>(
            T2[cur], Wk2, b2, C2, T2[nxt] + 64, 192, T3[cur] + 0, 256, nullptr);
        // cell3: T3[cur](256) -> h3 to T3[nxt]@128 and plain H3
        cell_mfma5<256, 128, 8><<<dim3(8 * 32), 256, 0, stream>>>(
            T3[cur], Wk3, b3, C3, T3[nxt] + 128, 256, nullptr, 0, H3);
        meo_kernel<<<dim3(4, 5, 2), 256, 0, stream>>>(H3, Wm, bm, out, t);
        aqi_kernel<<<dim3(NSTA, 2), 256, 0, stream>>>(H3, Wf1, bf1, Wf2, bf2, locs, out, t);
    }
}

// Round 10
// 583.511 us; speedup vs baseline: 4.9105x; 1.2096x over previous
//
#include <hip/hip_runtime.h>
#include <math.h>

// Problem constants
#define TX 6
#define NB 2
#define NSTA 35
#define PPLANE 1296      // 36*36 padded plane
#define PADW 36

typedef __attribute__((ext_vector_type(8))) _Float16 half8;
typedef __attribute__((ext_vector_type(4))) float f32x4;

__device__ __forceinline__ float sigf(float x) { return 1.0f / (1.0f + __expf(-x)); }

// Async global->LDS DMA, 16B per lane. LDS dest is wave-uniform base + lane*16.
__device__ __forceinline__ void gload_lds16(const void* g, void* l) {
    __builtin_amdgcn_global_load_lds(
        (const __attribute__((address_space(1))) void*)g,
        (__attribute__((address_space(3))) void*)l, 16, 0, 0);
}

// ---------------------------------------------------------------------------
// Weight prep: W (4CH,CTOT,5,5) fp32 gate-block-major ->
// Wk[d][mb][c32][lk][l16][e8] f16 : fragment = 512 f16 (16 m-rows x 32 cin).
// m = mb*16+l16 (= hc*4+gate), cin = c32*32+lk*8+e.
// ---------------------------------------------------------------------------
template <int CTOT, int CTOTP, int CH>
__global__ __launch_bounds__(256) void prep_w2(const float* __restrict__ W,
                                               _Float16* __restrict__ Wk) {
    constexpr int M = 4 * CH;
    const int total = 25 * M * CTOTP;
    int i = blockIdx.x * 256 + threadIdx.x;
    if (i >= total) return;
    const int e   = i & 7;
    const int l16 = (i >> 3) & 15;
    const int lk  = (i >> 7) & 3;
    const int c32 = (i >> 9) % (CTOTP / 32);
    const int rest = (i >> 9) / (CTOTP / 32);
    const int mb = rest % (M / 16);
    const int d  = rest / (M / 16);
    const int m = mb * 16 + l16;
    const int cin = c32 * 32 + lk * 8 + e;
    const int hc = m >> 2, g = m & 3;
    float v = 0.f;
    if (cin < CTOT) v = W[((g * CH + hc) * CTOT + cin) * 25 + d];
    Wk[i] = (_Float16)v;
}

// ---------------------------------------------------------------------------
// Stage x_t into T1[cur] channels [0,11), transposed padded layout (stride 96)
// ---------------------------------------------------------------------------
__global__ __launch_bounds__(256) void stage_x(const float* __restrict__ X,
                                               _Float16* __restrict__ T1, int t) {
    int i = blockIdx.x * 256 + threadIdx.x;   // 2*1024*16
    const int c = i & 15;
    const int pix = (i >> 4) & 1023;
    const int b = i >> 14;
    if (c >= 11 || b >= NB) return;
    const int y = pix >> 5, x = pix & 31;
    const int pp = (y + 2) * PADW + (x + 2);
    T1[((size_t)(b * PPLANE) + pp) * 96 + c] =
        (_Float16)X[(((b * TX + t) * 11 + c) << 10) + pix];
}

// ---------------------------------------------------------------------------
// MFMA ConvLSTM cell v5: DMA-staged B (double-buffered) + register
// software-pipelined A (depth PDA=5, 25%5==0 keeps ring aligned across chunk
// boundaries) and B (depth 3, re-prologued per chunk). All ring indices
// static under the fully-unrolled 25-tap loop (rule #20).
// GEMM: gates[M][N], M = 4*CH (m = hc*4+gate), N = 2048, K = 25*CTOTP.
// Block: 64m x 64n, 4 waves (2wm x 2wn), wave 32x32, acc 2x2.
// LDS slab (16B slots): slot = (rr*4 + c8)*36 + col; DMA decode = inverse.
// grid = NM * 32; mtile = bid % NM -> XCD round-robin keeps weights L2-local.
// ---------------------------------------------------------------------------
template <int CTOTP, int CH, int NM>
__global__ __launch_bounds__(256) void cell_mfma5(
    const _Float16* __restrict__ T,      // (2, 1296, CTOTP)
    const _Float16* __restrict__ Wk,     // chunked layout, see prep_w2
    const float* __restrict__ Bias,     // (4CH) gate-block layout
    float* __restrict__ Cst,            // (2, CH, 1024) fp32, in/out
    _Float16* __restrict__ outA, int strideA,   // pre-offset by channel base
    _Float16* __restrict__ outB, int strideB,   // optional
    float* __restrict__ outP)                   // optional plain (2,CH,1024)
{
    constexpr int M = 4 * CH;
    constexpr int NCH = CTOTP / 32;
    constexpr int PDA = 5;              // A prefetch depth; must divide 25
    // 2 buffers x 896 slots x 16B = 28672 B (864 real slots + 32 pad)
    __shared__ _Float16 slab[2 * 896 * 8];

    const int tid = threadIdx.x;
    const int wave = tid >> 6, lane = tid & 63;
    const int l16 = lane & 15, lk = lane >> 4;
    const int wm = wave >> 1, wn = wave & 1;
    const int bid = blockIdx.x;
    const int mtile = bid % NM;            // 64-row m tile
    const int ntile = bid / NM;            // 64-pixel n tile
    const int nbase = ntile * 64;
    const int b = nbase >> 10;
    const int y0 = (nbase & 1023) >> 5;    // first pixel row (even)
    const _Float16* Tb = T + (size_t)(b * PPLANE) * CTOTP;

    f32x4 acc[2][2] = {};

    // B base byte offsets: slab[r+dy][lk][x+dx] -> bbase + (dy*144+dx)*16
    int bbase[2];
#pragma unroll
    for (int nt = 0; nt < 2; ++nt) {
        const int pxl = wn * 32 + nt * 16 + l16;
        const int r = pxl >> 5, x = pxl & 31;
        bbase[nt] = (((r * 4 + lk) * 36) + x) * 16;
    }
    const int laneAoff = lk * 128 + l16 * 8;   // element offset within 512-frag

    // A-fragment load: chunk cc (runtime), tap dd (static), mt (static)
    auto loadA = [&](int cc, int dd, int mt) -> half8 {
        const int mb = mtile * 4 + wm * 2 + mt;
        return *(const half8*)(Wk +
            (size_t)(((dd * (M / 16) + mb) * NCH + cc) * 512 + laneAoff));
    };

    // Stage chunk c32 into buf[c32&1]: linear slot idx; decode inverts
    // slot = (rr*4+c8)*36 + col  (r6 bugfix decode).
    auto stage = [&](int c32) {
        char* dst = (char*)slab + (c32 & 1) * 14336;
#pragma unroll
        for (int k = 0; k < 4; ++k) {
            const int s = wave + k * 4;
            if (s < 14) {
                const int idx = (s << 6) + lane;
                const int col = idx % 36;
                const int rc  = idx / 36;          // rr*4 + c8 (rc=24: pad, unread)
                const int c8 = rc & 3, rr = rc >> 2;
                const _Float16* src = Tb +
                    (size_t)((y0 + rr) * PADW + col) * CTOTP + c32 * 32 + c8 * 8;
                gload_lds16(src, dst + idx * 16);
            }
        }
    };

    // A pipeline prologue: taps 0..PDA-1 of chunk 0
    half8 apre[PDA][2];
#pragma unroll
    for (int p = 0; p < PDA; ++p) {
        apre[p][0] = loadA(0, p, 0);
        apre[p][1] = loadA(0, p, 1);
    }

    stage(0);
    __syncthreads();                        // drains DMA (and prologue loads)

    for (int c32 = 0; c32 < NCH; ++c32) {
        if (c32 + 1 < NCH) stage(c32 + 1);  // async DMA into other buffer
        const char* sb = (const char*)slab + (c32 & 1) * 14336;

        // B pipeline prologue: taps 0..2 of this chunk
        half8 bpre[3][2];
#pragma unroll
        for (int p = 0; p < 3; ++p) {
            const int dy = p / 5, dx = p % 5;
            bpre[p][0] = *(const half8*)(sb + bbase[0] + (dy * 144 + dx) * 16);
            bpre[p][1] = *(const half8*)(sb + bbase[1] + (dy * 144 + dx) * 16);
        }

#pragma unroll
        for (int d = 0; d < 25; ++d) {
            // consume current fragments (slot = d % PDA, tap-aligned since 25%PDA==0)
            const half8 a0 = apre[d % PDA][0];
            const half8 a1 = apre[d % PDA][1];
            const half8 b0 = bpre[d % 3][0];
            const half8 b1 = bpre[d % 3][1];

            // refill A slot with tap d+PDA (slot (d+PDA)%PDA == d%PDA);
            // for d >= 25-PDA this is next chunk's tap d+PDA-25 (same slot).
            {
                const int dp = d + PDA;
                const int cstep = dp / 25;          // 0 or 1 (static)
                const int dd = dp % 25;             // static
                if (cstep == 0 || c32 + 1 < NCH) {
                    const int cc = c32 + cstep;
                    apre[d % PDA][0] = loadA(cc, dd, 0);
                    apre[d % PDA][1] = loadA(cc, dd, 1);
                }
            }
            // refill B slot with tap d+3 (within chunk)
            if (d + 3 < 25) {
                const int dy = (d + 3) / 5, dx = (d + 3) % 5;
                bpre[d % 3][0] = *(const half8*)(sb + bbase[0] + (dy * 144 + dx) * 16);
                bpre[d % 3][1] = *(const half8*)(sb + bbase[1] + (dy * 144 + dx) * 16);
            }

            acc[0][0] = __builtin_amdgcn_mfma_f32_16x16x32_f16(a0, b0, acc[0][0], 0, 0, 0);
            acc[0][1] = __builtin_amdgcn_mfma_f32_16x16x32_f16(a0, b1, acc[0][1], 0, 0, 0);
            acc[1][0] = __builtin_amdgcn_mfma_f32_16x16x32_f16(a1, b0, acc[1][0], 0, 0, 0);
            acc[1][1] = __builtin_amdgcn_mfma_f32_16x16x32_f16(a1, b1, acc[1][1], 0, 0, 0);
        }
        __syncthreads();   // waits compute ds_reads AND in-flight DMA/prefetch
    }

    // Epilogue: lane-local LSTM update. D row = lk*4 + r -> gates i,f,o,g of one hc.
#pragma unroll
    for (int mt = 0; mt < 2; ++mt) {
        const int hc = mtile * 16 + wm * 8 + mt * 4 + lk;
        const float bi = Bias[hc], bf = Bias[CH + hc];
        const float bo = Bias[2 * CH + hc], bg = Bias[3 * CH + hc];
#pragma unroll
        for (int nt = 0; nt < 2; ++nt) {
            const int pxl = wn * 32 + nt * 16 + l16;
            const int pix = (nbase & 1023) + pxl;
            const int y = pix >> 5, x = pix & 31;
            const f32x4 a = acc[mt][nt];
            const float gi = a[0] + bi, gf = a[1] + bf;
            const float go = a[2] + bo, gg = a[3] + bg;
            const int idx = ((b * CH + hc) << 10) + pix;
            const float c_old = Cst[idx];
            const float cn = sigf(gf) * c_old + sigf(gi) * tanhf(gg);
            const float hn = sigf(go) * tanhf(cn);
            Cst[idx] = cn;
            const _Float16 hh = (_Float16)hn;
            const size_t pp = (size_t)(b * PPLANE) + (y + 2) * PADW + (x + 2);
            outA[pp * strideA + hc] = hh;
            if (outB) outB[pp * strideB + hc] = hh;
            if (outP) outP[idx] = hn;
        }
    }
}

// ---------------------------------------------------------------------------
// meo head: 1x1 conv 128 -> 5 on plain fp32 H3
// ---------------------------------------------------------------------------
__global__ __launch_bounds__(256) void meo_kernel(const float* __restrict__ H3,
                                                  const float* __restrict__ Wm,
                                                  const float* __restrict__ bm,
                                                  float* __restrict__ out, int t) {
    const int pix = blockIdx.x * 256 + threadIdx.x;
    const int oc = blockIdx.y, b = blockIdx.z;
    const float* w = Wm + oc * 128;
    const float* h = H3 + ((b * 128) << 10) + pix;
    float a0 = 0.f, a1 = 0.f, a2 = 0.f, a3 = 0.f;
#pragma unroll
    for (int c = 0; c < 128; c += 4) {
        a0 = fmaf(w[c],     h[c << 10],       a0);
        a1 = fmaf(w[c + 1], h[(c + 1) << 10], a1);
        a2 = fmaf(w[c + 2], h[(c + 2) << 10], a2);
        a3 = fmaf(w[c + 3], h[(c + 3) << 10], a3);
    }
    out[2520 + (b * TX + t) * 5120 + (oc << 10) + pix] =
        ((a0 + a1) + (a2 + a3)) + bm[oc];
}

// ---------------------------------------------------------------------------
// aqi head v2: gather 128x3x3 patch -> MLP 1152->256->6. grid = (35, 2).
// r9 fix: layer-1 loop was a non-unrolled serial-dependent chain (1 load +
// 1 fma per iter, ~104 cyc/iter exposed L2 latency, 50 us/dispatch).
// Now: fully-unrolled k-loop, 8 independent accumulators -> 8 loads in
// flight, FMA latency amortized. Same for layer 2 (8 accs over 256).
// ---------------------------------------------------------------------------
__global__ __launch_bounds__(256) void aqi_kernel(const float* __restrict__ H3,
                                                  const float* __restrict__ Wf1,
                                                  const float* __restrict__ bf1,
                                                  const float* __restrict__ Wf2,
                                                  const float* __restrict__ bf2,
                                                  const int* __restrict__ locs,
                                                  float* __restrict__ out, int t) {
    __shared__ float feats[1152];
    __shared__ float hid[256];
    const int s = blockIdx.x, b = blockIdx.y, tid = threadIdx.x;
    const int y0 = locs[2 * s], x0 = locs[2 * s + 1];
    for (int k = tid; k < 1152; k += 256) {
        const int c = k / 9, r = k % 9;
        feats[k] = H3[((b * 128 + c) << 10) + (y0 + r / 3) * 32 + (x0 + r % 3)];
    }
    __syncthreads();
    {
        float ac[8] = {};
#pragma unroll
        for (int k = 0; k < 1152; k += 8) {
#pragma unroll
            for (int u = 0; u < 8; ++u)
                ac[u] = fmaf(feats[k + u], Wf1[(k + u) * 256 + tid], ac[u]);
        }
        const float acc = ((ac[0] + ac[1]) + (ac[2] + ac[3])) +
                          ((ac[4] + ac[5]) + (ac[6] + ac[7])) + bf1[tid];
        hid[tid] = tanhf(acc);
    }
    __syncthreads();
    if (tid < 6) {
        float ac[8] = {};
#pragma unroll
        for (int k = 0; k < 256; k += 8) {
#pragma unroll
            for (int u = 0; u < 8; ++u)
                ac[u] = fmaf(hid[k + u], Wf2[(k + u) * 6 + tid], ac[u]);
        }
        out[(b * TX + t) * 210 + s * 6 + tid] =
            ((ac[0] + ac[1]) + (ac[2] + ac[3])) +
            ((ac[4] + ac[5]) + (ac[6] + ac[7])) + bf2[tid];
    }
}

// ---------------------------------------------------------------------------
extern "C" void kernel_launch(void* const* d_in, const int* in_sizes, int n_in,
                              void* d_out, int out_size, void* d_ws, size_t ws_size,
                              hipStream_t stream) {
    const float* X   = (const float*)d_in[0];
    const float* W1  = (const float*)d_in[1];
    const float* b1  = (const float*)d_in[2];
    const float* W2  = (const float*)d_in[3];
    const float* b2  = (const float*)d_in[4];
    const float* W3  = (const float*)d_in[5];
    const float* b3  = (const float*)d_in[6];
    const float* Wm  = (const float*)d_in[7];
    const float* bm  = (const float*)d_in[8];
    const float* Wf1 = (const float*)d_in[9];
    const float* bf1 = (const float*)d_in[10];
    const float* Wf2 = (const float*)d_in[11];
    const float* bf2 = (const float*)d_in[12];
    const int* locs  = (const int*)d_in[13];
    float* out = (float*)d_out;

    // Byte-offset allocator, 256B aligned
    char* base = (char*)d_ws;
    size_t off = 0;
    auto alloc = [&](size_t bytes) -> char* {
        char* p = base + off;
        off = (off + bytes + 255) & ~(size_t)255;
        return p;
    };
    // Zeroed region: T buffers (f16), C states (fp32), H3
    _Float16* T1[2]; T1[0] = (_Float16*)alloc(2 * PPLANE * 96 * 2);
                     T1[1] = (_Float16*)alloc(2 * PPLANE * 96 * 2);
    _Float16* T2[2]; T2[0] = (_Float16*)alloc(2 * PPLANE * 192 * 2);
                     T2[1] = (_Float16*)alloc(2 * PPLANE * 192 * 2);
    _Float16* T3[2]; T3[0] = (_Float16*)alloc(2 * PPLANE * 256 * 2);
                     T3[1] = (_Float16*)alloc(2 * PPLANE * 256 * 2);
    float* C1 = (float*)alloc(2 * 64 * 1024 * 4);
    float* C2 = (float*)alloc(2 * 128 * 1024 * 4);
    float* C3 = (float*)alloc(2 * 128 * 1024 * 4);
    float* H3 = (float*)alloc(2 * 128 * 1024 * 4);
    const size_t zero_bytes = off;
    // Non-zeroed: weight buffers (fully written by prep each call)
    _Float16* Wk1 = (_Float16*)alloc((size_t)25 * 256 * 96 * 2);
    _Float16* Wk2 = (_Float16*)alloc((size_t)25 * 512 * 192 * 2);
    _Float16* Wk3 = (_Float16*)alloc((size_t)25 * 512 * 256 * 2);

    hipMemsetAsync(d_ws, 0, zero_bytes, stream);

    prep_w2<75, 96, 64><<<dim3((25 * 256 * 96 + 255) / 256), 256, 0, stream>>>(W1, Wk1);
    prep_w2<192, 192, 128><<<dim3((25 * 512 * 192 + 255) / 256), 256, 0, stream>>>(W2, Wk2);
    prep_w2<256, 256, 128><<<dim3((25 * 512 * 256 + 255) / 256), 256, 0, stream>>>(W3, Wk3);

    for (int t = 0; t < TX; ++t) {
        const int cur = t & 1, nxt = cur ^ 1;
        stage_x<<<dim3(128), 256, 0, stream>>>(X, T1[cur], t);
        // cell1: T1[cur](96) -> h1 to T1[nxt]@11 and T2[cur]@0   (M=256 -> NM=4)
        cell_mfma5<96, 64, 4><<<dim3(4 * 32), 256, 0, stream>>>(
            T1[cur], Wk1, b1, C1, T1[nxt] + 11, 96, T2[cur] + 0, 192, nullptr);
        // cell2: T2[cur](192) -> h2 to T2[nxt]@64 and T3[cur]@0  (M=512 -> NM=8)
        cell_mfma5<192, 128, 8><<<dim3(8 * 32), 256, 0, stream>>>(
            T2[cur], Wk2, b2, C2, T2[nxt] + 64, 192, T3[cur] + 0, 256, nullptr);
        // cell3: T3[cur](256) -> h3 to T3[nxt]@128 and plain H3
        cell_mfma5<256, 128, 8><<<dim3(8 * 32), 256, 0, stream>>>(
            T3[cur], Wk3, b3, C3, T3[nxt] + 128, 256, nullptr, 0, H3);
        meo_kernel<<<dim3(4, 5, 2), 256, 0, stream>>>(H3, Wm, bm, out, t);
        aqi_kernel<<<dim3(NSTA, 2), 256, 0, stream>>>(H3, Wf1, bf1, Wf2, bf2, locs, out, t);
    }
}